// Round 2
// baseline (863.497 us; speedup 1.0000x reference)
//
#include <hip/hip_runtime.h>

#define NB  4
#define CCH 256
#define NN  4096
#define KD  32
#define OD  256

typedef __attribute__((ext_vector_type(8))) __bf16 bf16x8;
typedef __attribute__((ext_vector_type(4))) float  floatx4;

__device__ __forceinline__ unsigned short f2bf(float f) {
    union { float f; unsigned u; } v; v.f = f;
    unsigned r = v.u + 0x7FFFu + ((v.u >> 16) & 1u);
    return (unsigned short)(r >> 16);
}

// ---------------------------------------------------------------------------
// Projection kernel (unchanged from R1):
//   chunk 0: Qb[b][n][k]  = (Wq x + bq)   (bf16, (N,K) layout = MFMA A-frag)
//   chunk 1: Ktb[b][n][k] = (Wk x + bk)   (bf16, (N,K) layout = MFMA B-frag)
//   chunks 2..9: Vb[b][o][n] = (Wv x + bv)
// ---------------------------------------------------------------------------
__global__ __launch_bounds__(256) void proj_kernel(
    const float* __restrict__ x,
    const float* __restrict__ Wq, const float* __restrict__ bq,
    const float* __restrict__ Wk, const float* __restrict__ bk,
    const float* __restrict__ Wv, const float* __restrict__ bv,
    unsigned short* __restrict__ Qb, unsigned short* __restrict__ Ktb,
    unsigned short* __restrict__ Vb)
{
    const int chunk = blockIdx.x;
    const int ntile = blockIdx.y;
    const int b     = blockIdx.z;
    const int tid   = threadIdx.x;
    const int n     = ntile * 256 + tid;

    const float* Wsrc;
    const float* bsrc;
    if (chunk == 0)      { Wsrc = Wq; bsrc = bq; }
    else if (chunk == 1) { Wsrc = Wk; bsrc = bk; }
    else                 { Wsrc = Wv + (size_t)(chunk - 2) * 32 * CCH;
                           bsrc = bv + (chunk - 2) * 32; }

    float acc[32];
    #pragma unroll
    for (int j = 0; j < 32; ++j) acc[j] = bsrc[j];

    const float* xp = x + (size_t)b * CCH * NN + n;
    for (int c = 0; c < CCH; c += 4) {
        float xv0 = xp[(size_t)(c + 0) * NN];
        float xv1 = xp[(size_t)(c + 1) * NN];
        float xv2 = xp[(size_t)(c + 2) * NN];
        float xv3 = xp[(size_t)(c + 3) * NN];
        #pragma unroll
        for (int j = 0; j < 32; ++j) {
            floatx4 w = *(const floatx4*)(Wsrc + j * CCH + c);
            acc[j] += w[0] * xv0;
            acc[j] += w[1] * xv1;
            acc[j] += w[2] * xv2;
            acc[j] += w[3] * xv3;
        }
    }

    if (chunk < 2) {
        unsigned short* dst = (chunk ? Ktb : Qb) + (size_t)(b * NN + n) * KD;
        __align__(16) unsigned short tmp[32];
        #pragma unroll
        for (int j = 0; j < 32; ++j) tmp[j] = f2bf(acc[j]);
        #pragma unroll
        for (int i = 0; i < 4; ++i)
            ((bf16x8*)dst)[i] = ((const bf16x8*)tmp)[i];
    } else {
        const int o0 = (chunk - 2) * 32;
        #pragma unroll
        for (int j = 0; j < 32; ++j)
            Vb[(size_t)(b * OD + o0 + j) * NN + n] = f2bf(acc[j]);
    }
}

// ---------------------------------------------------------------------------
// init_out: out[:B*O*N] = x  (skip connection base for atomic accumulation)
// ---------------------------------------------------------------------------
__global__ __launch_bounds__(256) void init_out(
    const float* __restrict__ x, float* __restrict__ out)
{
    const int i = blockIdx.x * 256 + threadIdx.x;   // 1M float4
    ((floatx4*)out)[i] = ((const floatx4*)x)[i];
}

// ---------------------------------------------------------------------------
// stats_partial: grid (4 colchunks, 256 rowtiles). Block = 64 rows x 1024 cols,
// 4 waves x 16 rows. Two QK passes: partial row-max, partial row-sumexp.
// ---------------------------------------------------------------------------
__global__ __launch_bounds__(256) void stats_partial(
    const unsigned short* __restrict__ Qb,
    const unsigned short* __restrict__ Ktb,
    float* __restrict__ pm, float* __restrict__ pl)
{
    const int tid  = threadIdx.x;
    const int wave = tid >> 6;
    const int lane = tid & 63;
    const int quad = lane >> 4;
    const int li   = lane & 15;
    const int cc   = blockIdx.x;
    const int b    = blockIdx.y >> 6;
    const int mw   = (blockIdx.y & 63) * 64 + wave * 16;

    const floatx4 zero = {0.f, 0.f, 0.f, 0.f};
    const bf16x8 aQ = *(const bf16x8*)(Qb + (size_t)(b * NN + mw + li) * KD + quad * 8);
    const unsigned short* ktbase =
        Ktb + (size_t)b * NN * KD + (size_t)cc * 1024 * KD + quad * 8;

    float mr[4] = {-1e30f, -1e30f, -1e30f, -1e30f};
    #pragma unroll 4
    for (int nt = 0; nt < 64; ++nt) {
        bf16x8 bK = *(const bf16x8*)(ktbase + (size_t)(nt * 16 + li) * KD);
        floatx4 s = __builtin_amdgcn_mfma_f32_16x16x32_bf16(aQ, bK, zero, 0, 0, 0);
        #pragma unroll
        for (int r = 0; r < 4; ++r) mr[r] = fmaxf(mr[r], s[r]);
    }
    #pragma unroll
    for (int r = 0; r < 4; ++r) {
        #pragma unroll
        for (int xm = 1; xm < 16; xm <<= 1)
            mr[r] = fmaxf(mr[r], __shfl_xor(mr[r], xm));
    }

    float lr[4] = {0.f, 0.f, 0.f, 0.f};
    #pragma unroll 4
    for (int nt = 0; nt < 64; ++nt) {
        bf16x8 bK = *(const bf16x8*)(ktbase + (size_t)(nt * 16 + li) * KD);
        floatx4 s = __builtin_amdgcn_mfma_f32_16x16x32_bf16(aQ, bK, zero, 0, 0, 0);
        #pragma unroll
        for (int r = 0; r < 4; ++r) lr[r] += __expf(s[r] - mr[r]);
    }
    #pragma unroll
    for (int r = 0; r < 4; ++r) {
        #pragma unroll
        for (int xm = 1; xm < 16; xm <<= 1)
            lr[r] += __shfl_xor(lr[r], xm);
    }

    if (li == 0) {
        const int base = cc * (NB * NN) + b * NN + mw + quad * 4;
        #pragma unroll
        for (int r = 0; r < 4; ++r) {
            pm[base + r] = mr[r];
            pl[base + r] = lr[r];
        }
    }
}

// ---------------------------------------------------------------------------
// stats_combine: merge 4 column-chunk partials -> final row max + 1/sum.
// ---------------------------------------------------------------------------
__global__ __launch_bounds__(256) void stats_combine(
    const float* __restrict__ pm, const float* __restrict__ pl,
    float* __restrict__ mf, float* __restrict__ lv)
{
    const int row = blockIdx.x * 256 + threadIdx.x;   // 16384 rows
    float m0 = pm[row], m1 = pm[NB * NN + row];
    float m2 = pm[2 * NB * NN + row], m3 = pm[3 * NB * NN + row];
    float m = fmaxf(fmaxf(m0, m1), fmaxf(m2, m3));
    float l = pl[row] * __expf(m0 - m)
            + pl[NB * NN + row] * __expf(m1 - m)
            + pl[2 * NB * NN + row] * __expf(m2 - m)
            + pl[3 * NB * NN + row] * __expf(m3 - m);
    mf[row] = m;
    lv[row] = 1.0f / l;
}

// ---------------------------------------------------------------------------
// emit_pv: grid (4 colchunks, 256 rowtiles), 4 waves x 16 rows x 1024 cols.
// QK recompute -> p = exp(s-m)*linv -> store attn; PV partial via LDS-staged V;
// epilogue: LDS O-transpose + atomicAdd(gamma*O) into out (pre-init = x).
// LDS = 40960 B exactly -> 4 blocks/CU = 16 waves/CU.
// ---------------------------------------------------------------------------
__global__ __launch_bounds__(256, 4) void emit_pv(
    const float* __restrict__ gammap,
    const unsigned short* __restrict__ Qb,
    const unsigned short* __restrict__ Ktb,
    const unsigned short* __restrict__ Vb,
    const float* __restrict__ mf, const float* __restrict__ lv,
    float* __restrict__ out, float* __restrict__ attn)
{
    __shared__ __align__(16) unsigned char smem[40960];
    unsigned short* Vlds = (unsigned short*)smem;                     // [256][68] bf16
    const int tid  = threadIdx.x;
    const int wave = tid >> 6;
    const int lane = tid & 63;
    const int quad = lane >> 4;
    const int li   = lane & 15;
    unsigned short* Plds = (unsigned short*)(smem + 34816) + wave * 576;  // [16][36]

    const int cc = blockIdx.x;
    const int b  = blockIdx.y >> 6;
    const int mw = (blockIdx.y & 63) * 64 + wave * 16;
    const int ncc = cc * 1024;

    const floatx4 zero = {0.f, 0.f, 0.f, 0.f};
    const bf16x8 aQ = *(const bf16x8*)(Qb + (size_t)(b * NN + mw + li) * KD + quad * 8);
    const unsigned short* ktbase = Ktb + (size_t)b * NN * KD + quad * 8;
    const unsigned short* vbase  = Vb + (size_t)b * OD * NN;

    float mrow[4], linv[4];
    #pragma unroll
    for (int r = 0; r < 4; ++r) {
        mrow[r] = mf[b * NN + mw + quad * 4 + r];
        linv[r] = lv[b * NN + mw + quad * 4 + r];
    }

    floatx4 oacc[16];
    #pragma unroll
    for (int ot = 0; ot < 16; ++ot) oacc[ot] = zero;

    for (int ch = 0; ch < 16; ++ch) {
        const int n0 = ncc + ch * 64;
        __syncthreads();
        #pragma unroll
        for (int i = 0; i < 8; ++i) {
            int linear = i * 256 + tid;
            int o = linear >> 3, part = linear & 7;
            *(bf16x8*)(Vlds + o * 68 + part * 8) =
                *(const bf16x8*)(vbase + (size_t)o * NN + n0 + part * 8);
        }
        __syncthreads();

        #pragma unroll
        for (int sub = 0; sub < 2; ++sub) {
            const int nn0 = n0 + sub * 32;
            bf16x8 bK0 = *(const bf16x8*)(ktbase + (size_t)(nn0 + li) * KD);
            bf16x8 bK1 = *(const bf16x8*)(ktbase + (size_t)(nn0 + 16 + li) * KD);
            floatx4 s0 = __builtin_amdgcn_mfma_f32_16x16x32_bf16(aQ, bK0, zero, 0, 0, 0);
            floatx4 s1 = __builtin_amdgcn_mfma_f32_16x16x32_bf16(aQ, bK1, zero, 0, 0, 0);
            #pragma unroll
            for (int r = 0; r < 4; ++r) {
                float p0 = __expf(s0[r] - mrow[r]) * linv[r];
                float p1 = __expf(s1[r] - mrow[r]) * linv[r];
                const int row = quad * 4 + r;
                float* ap = attn + (size_t)(b * NN + mw + row) * NN + nn0 + li;
                ap[0]  = p0;
                ap[16] = p1;
                Plds[row * 36 + li]      = f2bf(p0);
                Plds[row * 36 + 16 + li] = f2bf(p1);
            }
            bf16x8 aP = *(const bf16x8*)(Plds + li * 36 + quad * 8);
            #pragma unroll
            for (int ot = 0; ot < 16; ++ot) {
                bf16x8 bV = *(const bf16x8*)(Vlds + (ot * 16 + li) * 68 + sub * 32 + quad * 8);
                oacc[ot] = __builtin_amdgcn_mfma_f32_16x16x32_bf16(aP, bV, oacc[ot], 0, 0, 0);
            }
        }
    }

    // ---- epilogue: atomicAdd(gamma * O_partial) into out (out pre-init = x) ----
    __syncthreads();   // Olds overlaps Vlds/Plds
    const float g = gammap[0];
    float* Olds = (float*)(void*)smem + wave * 2560;   // [128][20] fp32 per wave
    #pragma unroll
    for (int h = 0; h < 2; ++h) {
        #pragma unroll
        for (int t = 0; t < 8; ++t) {
            const int ot = h * 8 + t;
            #pragma unroll
            for (int r = 0; r < 4; ++r)
                Olds[(t * 16 + li) * 20 + quad * 4 + r] = oacc[ot][r];
        }
        #pragma unroll
        for (int it = 0; it < 8; ++it) {
            int linear = it * 64 + lane;
            int ol = linear >> 2;
            int mp = (lane & 3) * 4;
            floatx4 ov = *(const floatx4*)(Olds + ol * 20 + mp);
            int o = h * 128 + ol;
            float* op = out + (size_t)(b * OD + o) * NN + mw + mp;
            atomicAdd(op + 0, g * ov[0]);
            atomicAdd(op + 1, g * ov[1]);
            atomicAdd(op + 2, g * ov[2]);
            atomicAdd(op + 3, g * ov[3]);
        }
        // Olds region reused by same wave only; wave-internal ordering suffices
    }
}

extern "C" void kernel_launch(void* const* d_in, const int* in_sizes, int n_in,
                              void* d_out, int out_size, void* d_ws, size_t ws_size,
                              hipStream_t stream) {
    const float* x     = (const float*)d_in[0];
    const float* Wq    = (const float*)d_in[1];
    const float* bq    = (const float*)d_in[2];
    const float* Wk    = (const float*)d_in[3];
    const float* bk    = (const float*)d_in[4];
    const float* Wv    = (const float*)d_in[5];
    const float* bv    = (const float*)d_in[6];
    const float* gamma = (const float*)d_in[7];

    float* out  = (float*)d_out;
    float* attn = out + (size_t)NB * OD * NN;

    unsigned short* Qb  = (unsigned short*)d_ws;        // 1 MB
    unsigned short* Ktb = Qb  + (size_t)NB * NN * KD;   // 1 MB
    unsigned short* Vb  = Ktb + (size_t)NB * NN * KD;   // 8 MB
    float* pm = (float*)(Vb + (size_t)NB * OD * NN);    // 4*B*N = 256 KB
    float* pl = pm + 4 * NB * NN;                       // 256 KB
    float* mfin = pl + 4 * NB * NN;                     // 64 KB
    float* lvin = mfin + NB * NN;                       // 64 KB

    proj_kernel<<<dim3(10, 16, 4), 256, 0, stream>>>(x, Wq, bq, Wk, bk, Wv, bv, Qb, Ktb, Vb);
    init_out<<<dim3(4096), 256, 0, stream>>>(x, out);
    stats_partial<<<dim3(4, 256), 256, 0, stream>>>(Qb, Ktb, pm, pl);
    stats_combine<<<dim3(64), 256, 0, stream>>>(pm, pl, mfin, lvin);
    emit_pv<<<dim3(4, 256), 256, 0, stream>>>(gamma, Qb, Ktb, Vb, mfin, lvin, out, attn);
}